// Round 1
// baseline (162.561 us; speedup 1.0000x reference)
//
#include <hip/hip_runtime.h>
#include <hip/hip_bf16.h>

// Reference collapses analytically:
//   tt = src + pose  =>  tt_c == src_c  =>  H = src_c @ src_c^T is symmetric PSD
//   => SVD of symmetric PSD has V == U (column-sign-consistent) => R = V U^T = I
//   => det(R) = 1 (no reflection branch)
//   => t = -I*src_mean + (src_mean + pose) = pose
// Output layout (concatenated flat, f32): R [B,3,3] then t [B,3].

__global__ void svd_identity_pose_kernel(const float* __restrict__ pose,
                                         float* __restrict__ out,
                                         int nR, int total) {
    int i = blockIdx.x * blockDim.x + threadIdx.x;
    if (i < nR) {
        // per-batch 3x3 identity: elements 0,4,8 of each 9-block are 1
        int r = i % 9;
        out[i] = (r == 0 || r == 4 || r == 8) ? 1.0f : 0.0f;
    } else if (i < total) {
        out[i] = pose[i - nR];   // t = pose (pose is [B,3,1] contiguous -> [B,3])
    }
}

extern "C" void kernel_launch(void* const* d_in, const int* in_sizes, int n_in,
                              void* d_out, int out_size, void* d_ws, size_t ws_size,
                              hipStream_t stream) {
    // inputs: d_in[0]=source [B,N,3] f32 (unused), d_in[1]=template (unused),
    //         d_in[2]=pose [B,3,1] f32
    const float* pose = (const float*)d_in[2];
    float* out = (float*)d_out;

    const int B = in_sizes[2] / 3;      // 4096
    const int nR = B * 9;               // R elements
    const int total = nR + B * 3;       // + t elements (== out_size)

    const int block = 256;
    const int grid = (total + block - 1) / block;
    svd_identity_pose_kernel<<<grid, block, 0, stream>>>(pose, out, nR, total);
}